// Round 6
// baseline (1141.900 us; speedup 1.0000x reference)
//
#include <hip/hip_runtime.h>
#include <stdint.h>

// Problem constants (B=4, N=4096, D=512, K=16384, NUM_Q=2)
constexpr int TT = 16384;   // tokens = B*N
constexpr int DD = 512;     // feature dim
constexpr int KK = 16384;   // codebook size
constexpr int TOPK = 8;     // exact-rescore candidates per token

typedef __bf16 bf16x8 __attribute__((ext_vector_type(8)));
typedef __bf16 bf16x4 __attribute__((ext_vector_type(4)));
typedef float f32x4 __attribute__((ext_vector_type(4)));

typedef const __attribute__((address_space(1))) void* gas_ptr;
typedef __attribute__((address_space(3))) void* las_ptr;

// Monotone float -> sortable u32, packed with index. u64 min == (min dist, then min idx),
// matching np.argmin first-occurrence tie-break.
__device__ __forceinline__ unsigned long long pack_di(float d, int idx) {
    uint32_t u = __float_as_uint(d);
    u = (u & 0x80000000u) ? ~u : (u | 0x80000000u);
    return ((unsigned long long)u << 32) | (uint32_t)idx;
}

__device__ __forceinline__ unsigned long long umin64(unsigned long long a,
                                                     unsigned long long b) {
    return a < b ? a : b;
}

// ---------------------------------------------------------------------------
// bf16-MFMA GEMM with fp32-grade accuracy via hi/lo split (3 products):
//   out[m][n] = sum_k Ain[m][k] * W[n][k] + bias[n]
// MODE 0: Ain = A       ; writes out0 (z), out1 (r copy), out2 (bf16 z)
// MODE 1: Ain = A - A2  ; writes out0 only
// 128x128 tile, BK=64, 4 waves 4x1 (32 rows x 128 cols each). N = 512.
// ---------------------------------------------------------------------------
template<int MODE>
__global__ __launch_bounds__(256)
void gemm_mfma(const float* __restrict__ A, const float* __restrict__ A2,
               const float* __restrict__ W, const float* __restrict__ bias,
               float* __restrict__ out0, float* __restrict__ out1,
               __bf16* __restrict__ out2)
{
    __shared__ __bf16 Ah[128 * 64], Al[128 * 64];
    __shared__ __bf16 Bh[128 * 64], Bl[128 * 64];   // 64 KB total
    const int tid = threadIdx.x;
    const int lane = tid & 63;
    const int w = tid >> 6;
    const int row0 = blockIdx.y * 128;
    const int col0 = blockIdx.x * 128;

    f32x4 acc[2][8] = {};

    // staging coords: thread t covers (row = i*16 + t>>4, fp32 cols scol..scol+3)
    const int sr = tid >> 4;            // 0..15
    const int scol = (tid & 15) * 4;    // 0..60
    // swizzled LDS col: chunk (8 bf16) position = (scol>>3) ^ (row&7); row&7 == sr&7
    const int lcol = (((scol >> 3) ^ (sr & 7)) << 3) + (scol & 7);

    // fragment LDS offsets (bf16 elems), row stride 64
    int a_off[2], b_off[8];
    #pragma unroll
    for (int mi = 0; mi < 2; ++mi) {
        const int ar = w * 32 + mi * 16 + (lane & 15);
        a_off[mi] = ar * 64 + (((lane >> 4) ^ (ar & 7)) << 3);
    }
    #pragma unroll
    for (int ni = 0; ni < 8; ++ni) {
        const int br = ni * 16 + (lane & 15);
        b_off[ni] = br * 64 + (((lane >> 4) ^ (br & 7)) << 3);
    }

    for (int kb = 0; kb < 512; kb += 64) {
        __syncthreads();
        #pragma unroll
        for (int i = 0; i < 8; ++i) {
            const int r = i * 16 + sr;
            float4 v = *(const float4*)(A + (size_t)(row0 + r) * 512 + kb + scol);
            if (MODE == 1) {
                const float4 u = *(const float4*)(A2 + (size_t)(row0 + r) * 512 + kb + scol);
                v.x -= u.x; v.y -= u.y; v.z -= u.z; v.w -= u.w;
            }
            bf16x4 hv, lv;
            hv[0] = (__bf16)v.x; hv[1] = (__bf16)v.y; hv[2] = (__bf16)v.z; hv[3] = (__bf16)v.w;
            lv[0] = (__bf16)(v.x - (float)hv[0]); lv[1] = (__bf16)(v.y - (float)hv[1]);
            lv[2] = (__bf16)(v.z - (float)hv[2]); lv[3] = (__bf16)(v.w - (float)hv[3]);
            *(bf16x4*)(Ah + r * 64 + lcol) = hv;
            *(bf16x4*)(Al + r * 64 + lcol) = lv;

            const float4 x = *(const float4*)(W + (size_t)(col0 + r) * 512 + kb + scol);
            bf16x4 hw, lw;
            hw[0] = (__bf16)x.x; hw[1] = (__bf16)x.y; hw[2] = (__bf16)x.z; hw[3] = (__bf16)x.w;
            lw[0] = (__bf16)(x.x - (float)hw[0]); lw[1] = (__bf16)(x.y - (float)hw[1]);
            lw[2] = (__bf16)(x.z - (float)hw[2]); lw[3] = (__bf16)(x.w - (float)hw[3]);
            *(bf16x4*)(Bh + r * 64 + lcol) = hw;
            *(bf16x4*)(Bl + r * 64 + lcol) = lw;
        }
        __syncthreads();
        #pragma unroll
        for (int s = 0; s < 2; ++s) {
            const int sx = s * 32;
            bf16x8 ah[2], al[2];
            #pragma unroll
            for (int mi = 0; mi < 2; ++mi) {
                ah[mi] = *(const bf16x8*)(Ah + (a_off[mi] ^ sx));
                al[mi] = *(const bf16x8*)(Al + (a_off[mi] ^ sx));
            }
            #pragma unroll
            for (int ni = 0; ni < 8; ++ni) {
                const bf16x8 bh = *(const bf16x8*)(Bh + (b_off[ni] ^ sx));
                const bf16x8 bl = *(const bf16x8*)(Bl + (b_off[ni] ^ sx));
                #pragma unroll
                for (int mi = 0; mi < 2; ++mi) {
                    acc[mi][ni] = __builtin_amdgcn_mfma_f32_16x16x32_bf16(ah[mi], bh, acc[mi][ni], 0, 0, 0);
                    acc[mi][ni] = __builtin_amdgcn_mfma_f32_16x16x32_bf16(ah[mi], bl, acc[mi][ni], 0, 0, 0);
                    acc[mi][ni] = __builtin_amdgcn_mfma_f32_16x16x32_bf16(al[mi], bh, acc[mi][ni], 0, 0, 0);
                }
            }
        }
    }

    // epilogue: C/D layout: col = lane&15, row = (lane>>4)*4 + reg
    #pragma unroll
    for (int mi = 0; mi < 2; ++mi) {
        #pragma unroll
        for (int reg = 0; reg < 4; ++reg) {
            const int row = row0 + w * 32 + mi * 16 + (lane >> 4) * 4 + reg;
            #pragma unroll
            for (int ni = 0; ni < 8; ++ni) {
                const int col = col0 + ni * 16 + (lane & 15);
                const float o = acc[mi][ni][reg] + bias[col];
                out0[(size_t)row * 512 + col] = o;
                if (MODE == 0) {
                    out1[(size_t)row * 512 + col] = o;
                    out2[(size_t)row * 512 + col] = (__bf16)o;
                }
            }
        }
    }
}

// ---------------------------------------------------------------------------
// Approx distance pass (bf16 MFMA, K=512, BK=64):
//   d[t][c] ~= csq[c] - 2 * (r16[t] . cb16[c])
// Block tile 128 tokens x 256 codes; 4 waves in 2x2, wave tile 64x128
// (acc[4][8]) -> per block per 32-k: 48 ds_read_b128 (576 cyc) vs 128 MFMA
// (620 cyc): MFMA-bound (R5's 4x1 mapping was LDS-issue-bound at 40:64).
// Per-row TOP-2 over each wave's 128 cols reduces in-wave -> winners table
// (tile = 128 cols, 128 tiles, 2 slots each; same layout as before).
// ---------------------------------------------------------------------------
__global__ __launch_bounds__(256)
void dist_approx(const __bf16* __restrict__ Rh,   // [TT][512]
                 const __bf16* __restrict__ Ch,   // [KK][512]
                 const float* __restrict__ csq,
                 unsigned long long* __restrict__ winners)
{
    __shared__ __bf16 As[128 * 64];
    __shared__ __bf16 Bs[256 * 64];   // 48 KB total
    const int tid = threadIdx.x;
    const int lane = tid & 63;
    const int w = tid >> 6;
    const int wm = w >> 1, wn = w & 1;
    const int row0 = blockIdx.y * 128;   // token tile
    const int col0 = blockIdx.x * 256;   // code tile

    f32x4 acc[4][8] = {};   // [mi][ni]: rows wm*64+mi*16, cols wn*128+ni*16

    // staging: lane -> (row-in-8 = lane>>3, chunk slot = lane&7), fetching
    // swizzled global chunk gc = (lane&7) ^ ((lane>>3)&7). Wave w stages
    // A rows [w*32,w*32+32) (4 calls) and B rows [w*64,w*64+64) (8 calls).
    const int gc = (lane & 7) ^ ((lane >> 3) & 7);
    const __bf16* Ab = Rh + (size_t)(row0 + w * 32 + (lane >> 3)) * 512 + gc * 8;
    const __bf16* Bb = Ch + (size_t)(col0 + w * 64 + (lane >> 3)) * 512 + gc * 8;
    __bf16* lA = As + (w * 32) * 64;
    __bf16* lB = Bs + (w * 64) * 64;

    // fragment offsets: LDS chunk = kc ^ (row&7); kc = s*4 + (lane>>4)
    int a_off[4], b_off[8];
    #pragma unroll
    for (int mi = 0; mi < 4; ++mi) {
        const int ar = wm * 64 + mi * 16 + (lane & 15);
        a_off[mi] = ar * 64 + (((lane >> 4) ^ (ar & 7)) << 3);
    }
    #pragma unroll
    for (int ni = 0; ni < 8; ++ni) {
        const int br = wn * 128 + ni * 16 + (lane & 15);
        b_off[ni] = br * 64 + (((lane >> 4) ^ (br & 7)) << 3);
    }

    for (int kb = 0; kb < 512; kb += 64) {
        __syncthreads();
        #pragma unroll
        for (int j = 0; j < 4; ++j)
            __builtin_amdgcn_global_load_lds(
                (gas_ptr)(Ab + (size_t)j * 8 * 512 + kb), (las_ptr)(lA + j * 8 * 64), 16, 0, 0);
        #pragma unroll
        for (int j = 0; j < 8; ++j)
            __builtin_amdgcn_global_load_lds(
                (gas_ptr)(Bb + (size_t)j * 8 * 512 + kb), (las_ptr)(lB + j * 8 * 64), 16, 0, 0);
        __syncthreads();
        #pragma unroll
        for (int s = 0; s < 2; ++s) {
            const int sx = s * 32;
            bf16x8 af[4], bfr[8];
            #pragma unroll
            for (int mi = 0; mi < 4; ++mi) af[mi] = *(const bf16x8*)(As + (a_off[mi] ^ sx));
            #pragma unroll
            for (int ni = 0; ni < 8; ++ni) bfr[ni] = *(const bf16x8*)(Bs + (b_off[ni] ^ sx));
            #pragma unroll
            for (int mi = 0; mi < 4; ++mi)
                #pragma unroll
                for (int ni = 0; ni < 8; ++ni)
                    acc[mi][ni] = __builtin_amdgcn_mfma_f32_16x16x32_bf16(
                        af[mi], bfr[ni], acc[mi][ni], 0, 0, 0);
        }
    }

    // epilogue: per token-row top-2 over this wave's 128 cols -> two u64 stores
    // C/D layout (16x16x32): col = lane&15, row = (lane>>4)*4 + reg
    float csv[8];
    #pragma unroll
    for (int ni = 0; ni < 8; ++ni)
        csv[ni] = csq[col0 + wn * 128 + ni * 16 + (lane & 15)];

    const int tile = blockIdx.x * 2 + wn;   // 0..127
    #pragma unroll
    for (int mi = 0; mi < 4; ++mi) {
        #pragma unroll
        for (int reg = 0; reg < 4; ++reg) {
            unsigned long long b = ~0ull, s = ~0ull;
            #pragma unroll
            for (int ni = 0; ni < 8; ++ni) {
                const float d = fmaf(-2.0f, acc[mi][ni][reg], csv[ni]);
                const unsigned long long x =
                    pack_di(d, col0 + wn * 128 + ni * 16 + (lane & 15));
                const unsigned long long nb = umin64(b, x);
                s = umin64(s, b ^ x ^ nb);   // max(b,x) = b^x^min(b,x)
                b = nb;
            }
            #pragma unroll
            for (int m = 1; m < 16; m <<= 1) {
                const unsigned long long ob = __shfl_xor(b, m, 16);
                const unsigned long long os = __shfl_xor(s, m, 16);
                const unsigned long long nb = umin64(b, ob);
                s = umin64(umin64(s, os), b ^ ob ^ nb);
                b = nb;
            }
            if ((lane & 15) == 0) {
                const int row = row0 + wm * 64 + mi * 16 + (lane >> 4) * 4 + reg;
                winners[(size_t)row * 256 + tile * 2 + 0] = b;
                winners[(size_t)row * 256 + tile * 2 + 1] = s;
            }
        }
    }
}

// ---------------------------------------------------------------------------
// Per token (one wave): approx top-8 of the 256 stored candidates, exact fp32
// rescore, pick true argmin (np tie-break), then fused residual update:
//   r[t] -= cb[best];  r16[t] = bf16(r[t])
// ---------------------------------------------------------------------------
__global__ __launch_bounds__(256)
void select_rescore(const unsigned long long* __restrict__ winners,
                    const float* __restrict__ CB, const float* __restrict__ csq,
                    float* __restrict__ R, __bf16* __restrict__ R16)
{
    const int w = threadIdx.x >> 6;
    const int lane = threadIdx.x & 63;
    const int token = blockIdx.x * 4 + w;

    const unsigned long long* wt = winners + (size_t)token * 256;
    unsigned long long v[4];
    #pragma unroll
    for (int j = 0; j < 4; ++j) v[j] = wt[lane * 4 + j];

    unsigned long long cand[TOPK];
    #pragma unroll
    for (int t = 0; t < TOPK; ++t) {
        unsigned long long mm = umin64(umin64(v[0], v[1]), umin64(v[2], v[3]));
        #pragma unroll
        for (int m = 1; m < 64; m <<= 1)
            mm = umin64(mm, __shfl_xor(mm, m, 64));
        cand[t] = mm;
        #pragma unroll
        for (int j = 0; j < 4; ++j) if (v[j] == mm) v[j] = ~0ull;
    }

    // exact rescore in fp32
    float4 r0 = *(const float4*)(R + (size_t)token * 512 + lane * 8);
    float4 r1 = *(const float4*)(R + (size_t)token * 512 + lane * 8 + 4);

    unsigned long long best = ~0ull;
    #pragma unroll
    for (int t = 0; t < TOPK; ++t) {
        const int col = (int)(cand[t] & 0xFFFFFFFFull);
        const float4 c0 = *(const float4*)(CB + (size_t)col * 512 + lane * 8);
        const float4 c1 = *(const float4*)(CB + (size_t)col * 512 + lane * 8 + 4);
        float dot = r0.x * c0.x;
        dot = fmaf(r0.y, c0.y, dot); dot = fmaf(r0.z, c0.z, dot);
        dot = fmaf(r0.w, c0.w, dot); dot = fmaf(r1.x, c1.x, dot);
        dot = fmaf(r1.y, c1.y, dot); dot = fmaf(r1.z, c1.z, dot);
        dot = fmaf(r1.w, c1.w, dot);
        #pragma unroll
        for (int m = 1; m < 64; m <<= 1) dot += __shfl_xor(dot, m, 64);
        const float d = fmaf(-2.0f, dot, csq[col]);
        best = umin64(best, pack_di(d, col));
    }

    const int bcol = (int)(best & 0xFFFFFFFFull);
    const float4 c0 = *(const float4*)(CB + (size_t)bcol * 512 + lane * 8);
    const float4 c1 = *(const float4*)(CB + (size_t)bcol * 512 + lane * 8 + 4);
    r0.x -= c0.x; r0.y -= c0.y; r0.z -= c0.z; r0.w -= c0.w;
    r1.x -= c1.x; r1.y -= c1.y; r1.z -= c1.z; r1.w -= c1.w;
    *(float4*)(R + (size_t)token * 512 + lane * 8) = r0;
    *(float4*)(R + (size_t)token * 512 + lane * 8 + 4) = r1;
    bf16x8 h;
    h[0] = (__bf16)r0.x; h[1] = (__bf16)r0.y; h[2] = (__bf16)r0.z; h[3] = (__bf16)r0.w;
    h[4] = (__bf16)r1.x; h[5] = (__bf16)r1.y; h[6] = (__bf16)r1.z; h[7] = (__bf16)r1.w;
    *(bf16x8*)(R16 + (size_t)token * 512 + lane * 8) = h;
}

// ---------------------------------------------------------------------------
// Codebook prep (fused): c_sq[k] = ||cb[k]||^2 (fp32) and cb16 = bf16(cb)
// one wave per row
// ---------------------------------------------------------------------------
__global__ __launch_bounds__(256)
void prep_cb(const float* __restrict__ CB, float* __restrict__ c_sq,
             __bf16* __restrict__ cb16)
{
    const int wave = threadIdx.x >> 6;
    const int lane = threadIdx.x & 63;
    const int row = blockIdx.x * 4 + wave;
    const float* p = CB + (size_t)row * DD + lane * 8;
    const float4 a = *(const float4*)p;
    const float4 b = *(const float4*)(p + 4);
    bf16x8 h;
    h[0] = (__bf16)a.x; h[1] = (__bf16)a.y; h[2] = (__bf16)a.z; h[3] = (__bf16)a.w;
    h[4] = (__bf16)b.x; h[5] = (__bf16)b.y; h[6] = (__bf16)b.z; h[7] = (__bf16)b.w;
    *(bf16x8*)(cb16 + (size_t)row * DD + lane * 8) = h;
    float s = a.x*a.x + a.y*a.y + a.z*a.z + a.w*a.w
            + b.x*b.x + b.y*b.y + b.z*b.z + b.w*b.w;
    #pragma unroll
    for (int m = 1; m < 64; m <<= 1) s += __shfl_xor(s, m, 64);
    if (lane == 0) c_sq[row] = s;
}

// ---------------------------------------------------------------------------
extern "C" void kernel_launch(void* const* d_in, const int* in_sizes, int n_in,
                              void* d_out, int out_size, void* d_ws, size_t ws_size,
                              hipStream_t stream)
{
    const float* x    = (const float*)d_in[0];
    const float* encw = (const float*)d_in[1];
    const float* encb = (const float*)d_in[2];
    const float* cb   = (const float*)d_in[3];
    const float* decw = (const float*)d_in[4];
    const float* decb = (const float*)d_in[5];
    float* out = (float*)d_out;

    // ws layout: z (32MB) | r (32MB) | cb16 (16MB) | r16 (16MB) | csq  (~96.1MB)
    float* z    = (float*)d_ws;                                  // TT*DD f32
    float* r    = z + (size_t)TT * DD;                           // TT*DD f32
    __bf16* cb16 = (__bf16*)(r + (size_t)TT * DD);               // KK*512 bf16
    __bf16* r16  = cb16 + (size_t)KK * DD;                       // TT*512 bf16
    float* csq  = (float*)(r16 + (size_t)TT * DD);               // KK f32
    // winners table lives in d_out (32MB) — dead before decoder writes out
    unsigned long long* winners = (unsigned long long*)d_out;    // TT*256 u64

    const dim3 blk(256);

    // encoder (MFMA hi/lo): z = x @ enc_w^T + enc_b ; r = z ; r16 = bf16(z)
    gemm_mfma<0><<<dim3(DD / 128, TT / 128), blk, 0, stream>>>(
        x, nullptr, encw, encb, z, r, r16);

    // codebook: exact squared norms + bf16 copy (fused, once per call)
    prep_cb<<<dim3(KK / 4), blk, 0, stream>>>(cb, csq, cb16);

    for (int s = 0; s < 2; ++s) {
        dist_approx<<<dim3(KK / 256, TT / 128), blk, 0, stream>>>(r16, cb16, csq, winners);
        select_rescore<<<dim3(TT / 4), blk, 0, stream>>>(winners, cb, csq, r, r16);
    }

    // decoder (MFMA hi/lo): out = (z - r) @ dec_w^T + dec_b
    gemm_mfma<1><<<dim3(DD / 128, TT / 128), blk, 0, stream>>>(
        z, r, decw, decb, out, nullptr, nullptr);
}

// Round 7
// 1090.188 us; speedup vs baseline: 1.0474x; 1.0474x over previous
//
#include <hip/hip_runtime.h>
#include <stdint.h>

// Problem constants (B=4, N=4096, D=512, K=16384, NUM_Q=2)
constexpr int TT = 16384;   // tokens = B*N
constexpr int DD = 512;     // feature dim
constexpr int KK = 16384;   // codebook size
constexpr int TOPK = 8;     // exact-rescore candidates per token

typedef __bf16 bf16x8 __attribute__((ext_vector_type(8)));
typedef __bf16 bf16x4 __attribute__((ext_vector_type(4)));
typedef float f32x4 __attribute__((ext_vector_type(4)));

typedef const __attribute__((address_space(1))) void* gas_ptr;
typedef __attribute__((address_space(3))) void* las_ptr;

// Monotone float -> sortable u32, packed with index. u64 min == (min dist, then min idx),
// matching np.argmin first-occurrence tie-break. (used in exact rescore)
__device__ __forceinline__ unsigned long long pack_di(float d, int idx) {
    uint32_t u = __float_as_uint(d);
    u = (u & 0x80000000u) ? ~u : (u | 0x80000000u);
    return ((unsigned long long)u << 32) | (uint32_t)idx;
}

__device__ __forceinline__ unsigned long long umin64(unsigned long long a,
                                                     unsigned long long b) {
    return a < b ? a : b;
}
__device__ __forceinline__ uint32_t umin32(uint32_t a, uint32_t b) { return a < b ? a : b; }
__device__ __forceinline__ uint32_t umax32(uint32_t a, uint32_t b) { return a > b ? a : b; }

// fp32 -> sortable u32 (monotone)
__device__ __forceinline__ uint32_t sortable(float d) {
    uint32_t u = __float_as_uint(d);
    return u ^ ((uint32_t)((int32_t)u >> 31) | 0x80000000u);
}

// ---------------------------------------------------------------------------
// bf16-MFMA GEMM with fp32-grade accuracy via hi/lo split (3 products):
//   out[m][n] = sum_k Ain[m][k] * W[n][k] + bias[n]
// MODE 0: Ain = A       ; writes out0 (z), out1 (r copy), out2 (bf16 z)
// MODE 1: Ain = A - A2  ; writes out0 only
// 128x128 tile, BK=64, 4 waves 4x1 (32 rows x 128 cols each). N = 512.
// ---------------------------------------------------------------------------
template<int MODE>
__global__ __launch_bounds__(256)
void gemm_mfma(const float* __restrict__ A, const float* __restrict__ A2,
               const float* __restrict__ W, const float* __restrict__ bias,
               float* __restrict__ out0, float* __restrict__ out1,
               __bf16* __restrict__ out2)
{
    __shared__ __bf16 Ah[128 * 64], Al[128 * 64];
    __shared__ __bf16 Bh[128 * 64], Bl[128 * 64];   // 64 KB total
    const int tid = threadIdx.x;
    const int lane = tid & 63;
    const int w = tid >> 6;
    const int row0 = blockIdx.y * 128;
    const int col0 = blockIdx.x * 128;

    f32x4 acc[2][8] = {};

    // staging coords: thread t covers (row = i*16 + t>>4, fp32 cols scol..scol+3)
    const int sr = tid >> 4;            // 0..15
    const int scol = (tid & 15) * 4;    // 0..60
    const int lcol = (((scol >> 3) ^ (sr & 7)) << 3) + (scol & 7);

    int a_off[2], b_off[8];
    #pragma unroll
    for (int mi = 0; mi < 2; ++mi) {
        const int ar = w * 32 + mi * 16 + (lane & 15);
        a_off[mi] = ar * 64 + (((lane >> 4) ^ (ar & 7)) << 3);
    }
    #pragma unroll
    for (int ni = 0; ni < 8; ++ni) {
        const int br = ni * 16 + (lane & 15);
        b_off[ni] = br * 64 + (((lane >> 4) ^ (br & 7)) << 3);
    }

    for (int kb = 0; kb < 512; kb += 64) {
        __syncthreads();
        #pragma unroll
        for (int i = 0; i < 8; ++i) {
            const int r = i * 16 + sr;
            float4 v = *(const float4*)(A + (size_t)(row0 + r) * 512 + kb + scol);
            if (MODE == 1) {
                const float4 u = *(const float4*)(A2 + (size_t)(row0 + r) * 512 + kb + scol);
                v.x -= u.x; v.y -= u.y; v.z -= u.z; v.w -= u.w;
            }
            bf16x4 hv, lv;
            hv[0] = (__bf16)v.x; hv[1] = (__bf16)v.y; hv[2] = (__bf16)v.z; hv[3] = (__bf16)v.w;
            lv[0] = (__bf16)(v.x - (float)hv[0]); lv[1] = (__bf16)(v.y - (float)hv[1]);
            lv[2] = (__bf16)(v.z - (float)hv[2]); lv[3] = (__bf16)(v.w - (float)hv[3]);
            *(bf16x4*)(Ah + r * 64 + lcol) = hv;
            *(bf16x4*)(Al + r * 64 + lcol) = lv;

            const float4 x = *(const float4*)(W + (size_t)(col0 + r) * 512 + kb + scol);
            bf16x4 hw, lw;
            hw[0] = (__bf16)x.x; hw[1] = (__bf16)x.y; hw[2] = (__bf16)x.z; hw[3] = (__bf16)x.w;
            lw[0] = (__bf16)(x.x - (float)hw[0]); lw[1] = (__bf16)(x.y - (float)hw[1]);
            lw[2] = (__bf16)(x.z - (float)hw[2]); lw[3] = (__bf16)(x.w - (float)hw[3]);
            *(bf16x4*)(Bh + r * 64 + lcol) = hw;
            *(bf16x4*)(Bl + r * 64 + lcol) = lw;
        }
        __syncthreads();
        #pragma unroll
        for (int s = 0; s < 2; ++s) {
            const int sx = s * 32;
            bf16x8 ah[2], al[2];
            #pragma unroll
            for (int mi = 0; mi < 2; ++mi) {
                ah[mi] = *(const bf16x8*)(Ah + (a_off[mi] ^ sx));
                al[mi] = *(const bf16x8*)(Al + (a_off[mi] ^ sx));
            }
            #pragma unroll
            for (int ni = 0; ni < 8; ++ni) {
                const bf16x8 bh = *(const bf16x8*)(Bh + (b_off[ni] ^ sx));
                const bf16x8 bl = *(const bf16x8*)(Bl + (b_off[ni] ^ sx));
                #pragma unroll
                for (int mi = 0; mi < 2; ++mi) {
                    acc[mi][ni] = __builtin_amdgcn_mfma_f32_16x16x32_bf16(ah[mi], bh, acc[mi][ni], 0, 0, 0);
                    acc[mi][ni] = __builtin_amdgcn_mfma_f32_16x16x32_bf16(ah[mi], bl, acc[mi][ni], 0, 0, 0);
                    acc[mi][ni] = __builtin_amdgcn_mfma_f32_16x16x32_bf16(al[mi], bh, acc[mi][ni], 0, 0, 0);
                }
            }
        }
    }

    #pragma unroll
    for (int mi = 0; mi < 2; ++mi) {
        #pragma unroll
        for (int reg = 0; reg < 4; ++reg) {
            const int row = row0 + w * 32 + mi * 16 + (lane >> 4) * 4 + reg;
            #pragma unroll
            for (int ni = 0; ni < 8; ++ni) {
                const int col = col0 + ni * 16 + (lane & 15);
                const float o = acc[mi][ni][reg] + bias[col];
                out0[(size_t)row * 512 + col] = o;
                if (MODE == 0) {
                    out1[(size_t)row * 512 + col] = o;
                    out2[(size_t)row * 512 + col] = (__bf16)o;
                }
            }
        }
    }
}

// ---------------------------------------------------------------------------
// Approx distance pass (bf16 MFMA, K=512, BK=32):
//   d[t][c] ~= csq[c] - 2 * (r16[t] . cb16[c])
// 128x128 block, 4 waves 2x2 (wave tile 64x64, acc[4][4] = 64 AGPR ->
// ~3 blocks/CU). Per block per 32-k: 32 ds_read_b128 vs 64 MFMA (m97 shape).
// Epilogue: per token-row TOP-2 over the wave's 64 cols using u32 sort keys
// (monotone fp32 with low 6 bits = local col; quantization ±0.016 << bf16
// noise) -> min/max u32 merges + 32-bit shuffles. winners = u32[TT][512],
// slot (tile*2 + {0,1}), tile = 64 cols.
// ---------------------------------------------------------------------------
__global__ __launch_bounds__(256)
void dist_approx(const __bf16* __restrict__ Rh,   // [TT][512]
                 const __bf16* __restrict__ Ch,   // [KK][512]
                 const float* __restrict__ csq,
                 uint32_t* __restrict__ winners)
{
    __shared__ __bf16 As[128 * 32];
    __shared__ __bf16 Bs[128 * 32];   // 16 KB total
    const int tid = threadIdx.x;
    const int lane = tid & 63;
    const int w = tid >> 6;
    const int wm = w >> 1, wn = w & 1;
    const int row0 = blockIdx.y * 128;   // token tile
    const int col0 = blockIdx.x * 128;   // code tile

    f32x4 acc[4][4] = {};   // [mi][ni]

    // staging: wave w stages tile rows [w*32, w*32+32) in 2 calls of 16 rows
    const int srow0 = w * 32 + (lane >> 2);
    const int srow1 = srow0 + 16;
    const int gc0 = (lane & 3) ^ ((srow0 >> 1) & 3);  // swizzled 8-elem chunk
    const int gc1 = (lane & 3) ^ ((srow1 >> 1) & 3);
    __bf16* ldsA0 = As + (w * 32 + 0) * 32;
    __bf16* ldsA1 = As + (w * 32 + 16) * 32;
    __bf16* ldsB0 = Bs + (w * 32 + 0) * 32;
    __bf16* ldsB1 = Bs + (w * 32 + 16) * 32;

    // loop-invariant fragment LDS offsets, swizzle-compensated
    int a_off[4], b_off[4];
    #pragma unroll
    for (int i = 0; i < 4; ++i) {
        const int ar = wm * 64 + i * 16 + (lane & 15);
        a_off[i] = ar * 32 + (((lane >> 4) ^ ((ar >> 1) & 3)) << 3);
        const int br = wn * 64 + i * 16 + (lane & 15);
        b_off[i] = br * 32 + (((lane >> 4) ^ ((br >> 1) & 3)) << 3);
    }

    for (int kb = 0; kb < 512; kb += 32) {
        __syncthreads();
        __builtin_amdgcn_global_load_lds(
            (gas_ptr)(Rh + (size_t)(row0 + srow0) * 512 + kb + gc0 * 8), (las_ptr)ldsA0, 16, 0, 0);
        __builtin_amdgcn_global_load_lds(
            (gas_ptr)(Rh + (size_t)(row0 + srow1) * 512 + kb + gc1 * 8), (las_ptr)ldsA1, 16, 0, 0);
        __builtin_amdgcn_global_load_lds(
            (gas_ptr)(Ch + (size_t)(col0 + srow0) * 512 + kb + gc0 * 8), (las_ptr)ldsB0, 16, 0, 0);
        __builtin_amdgcn_global_load_lds(
            (gas_ptr)(Ch + (size_t)(col0 + srow1) * 512 + kb + gc1 * 8), (las_ptr)ldsB1, 16, 0, 0);
        __syncthreads();

        bf16x8 af[4], bfr[4];
        #pragma unroll
        for (int i = 0; i < 4; ++i) af[i]  = *(const bf16x8*)(As + a_off[i]);
        #pragma unroll
        for (int i = 0; i < 4; ++i) bfr[i] = *(const bf16x8*)(Bs + b_off[i]);
        #pragma unroll
        for (int mi = 0; mi < 4; ++mi)
            #pragma unroll
            for (int ni = 0; ni < 4; ++ni)
                acc[mi][ni] = __builtin_amdgcn_mfma_f32_16x16x32_bf16(
                    af[mi], bfr[ni], acc[mi][ni], 0, 0, 0);
    }

    // epilogue: per token-row top-2 over this wave's 64 cols, u32 keys.
    // C/D layout (16x16x32): col = lane&15, row = (lane>>4)*4 + reg
    float csv[4];
    #pragma unroll
    for (int ni = 0; ni < 4; ++ni)
        csv[ni] = csq[col0 + wn * 64 + ni * 16 + (lane & 15)];

    const int tile = blockIdx.x * 2 + wn;   // 0..255 (64-col granule)
    #pragma unroll
    for (int mi = 0; mi < 4; ++mi) {
        #pragma unroll
        for (int reg = 0; reg < 4; ++reg) {
            uint32_t b = 0xFFFFFFFFu, s = 0xFFFFFFFFu;
            #pragma unroll
            for (int ni = 0; ni < 4; ++ni) {
                const float d = fmaf(-2.0f, acc[mi][ni][reg], csv[ni]);
                const uint32_t key = (sortable(d) & 0xFFFFFFC0u)
                                   | (uint32_t)(ni * 16 + (lane & 15));
                const uint32_t nb = umin32(b, key);
                s = umin32(s, umax32(b, key));
                b = nb;
            }
            #pragma unroll
            for (int m = 1; m < 16; m <<= 1) {
                const uint32_t ob = __shfl_xor((int)b, m, 16);
                const uint32_t os = __shfl_xor((int)s, m, 16);
                const uint32_t nb = umin32(b, ob);
                s = umin32(umin32(s, os), umax32(b, ob));
                b = nb;
            }
            if ((lane & 15) == 0) {
                const int row = row0 + wm * 64 + mi * 16 + (lane >> 4) * 4 + reg;
                uint2 v; v.x = b; v.y = s;
                *(uint2*)(winners + (size_t)row * 512 + tile * 2) = v;
            }
        }
    }
}

// ---------------------------------------------------------------------------
// Per token (one wave): approx top-8 of the 512 stored u32 keys, exact fp32
// rescore, pick true argmin (np tie-break), then fused residual update:
//   r[t] -= cb[best];  r16[t] = bf16(r[t])
// key -> global col: slot j holds tile j>>1 (64-col granule), col low 6 bits.
// ---------------------------------------------------------------------------
__global__ __launch_bounds__(256)
void select_rescore(const uint32_t* __restrict__ winners,
                    const float* __restrict__ CB, const float* __restrict__ csq,
                    float* __restrict__ R, __bf16* __restrict__ R16)
{
    const int w = threadIdx.x >> 6;
    const int lane = threadIdx.x & 63;
    const int token = blockIdx.x * 4 + w;

    const uint32_t* wt = winners + (size_t)token * 512;
    uint4 q0 = *(const uint4*)(wt + lane * 8);
    uint4 q1 = *(const uint4*)(wt + lane * 8 + 4);
    uint32_t k32[8] = {q0.x, q0.y, q0.z, q0.w, q1.x, q1.y, q1.z, q1.w};

    unsigned long long v[8];
    #pragma unroll
    for (int j = 0; j < 8; ++j) {
        const int gcol = ((lane * 8 + j) >> 1) * 64 + (int)(k32[j] & 63u);
        v[j] = ((unsigned long long)k32[j] << 32) | (uint32_t)gcol;
    }

    unsigned long long cand[TOPK];
    #pragma unroll
    for (int t = 0; t < TOPK; ++t) {
        unsigned long long mm = v[0];
        #pragma unroll
        for (int j = 1; j < 8; ++j) mm = umin64(mm, v[j]);
        #pragma unroll
        for (int m = 1; m < 64; m <<= 1)
            mm = umin64(mm, __shfl_xor(mm, m, 64));
        cand[t] = mm;
        #pragma unroll
        for (int j = 0; j < 8; ++j) if (v[j] == mm) v[j] = ~0ull;
    }

    // exact rescore in fp32
    float4 r0 = *(const float4*)(R + (size_t)token * 512 + lane * 8);
    float4 r1 = *(const float4*)(R + (size_t)token * 512 + lane * 8 + 4);

    unsigned long long best = ~0ull;
    #pragma unroll
    for (int t = 0; t < TOPK; ++t) {
        const int col = (int)(cand[t] & 0xFFFFFFFFull);
        const float4 c0 = *(const float4*)(CB + (size_t)col * 512 + lane * 8);
        const float4 c1 = *(const float4*)(CB + (size_t)col * 512 + lane * 8 + 4);
        float dot = r0.x * c0.x;
        dot = fmaf(r0.y, c0.y, dot); dot = fmaf(r0.z, c0.z, dot);
        dot = fmaf(r0.w, c0.w, dot); dot = fmaf(r1.x, c1.x, dot);
        dot = fmaf(r1.y, c1.y, dot); dot = fmaf(r1.z, c1.z, dot);
        dot = fmaf(r1.w, c1.w, dot);
        #pragma unroll
        for (int m = 1; m < 64; m <<= 1) dot += __shfl_xor(dot, m, 64);
        const float d = fmaf(-2.0f, dot, csq[col]);
        best = umin64(best, pack_di(d, col));
    }

    const int bcol = (int)(best & 0xFFFFFFFFull);
    const float4 c0 = *(const float4*)(CB + (size_t)bcol * 512 + lane * 8);
    const float4 c1 = *(const float4*)(CB + (size_t)bcol * 512 + lane * 8 + 4);
    r0.x -= c0.x; r0.y -= c0.y; r0.z -= c0.z; r0.w -= c0.w;
    r1.x -= c1.x; r1.y -= c1.y; r1.z -= c1.z; r1.w -= c1.w;
    *(float4*)(R + (size_t)token * 512 + lane * 8) = r0;
    *(float4*)(R + (size_t)token * 512 + lane * 8 + 4) = r1;
    bf16x8 h;
    h[0] = (__bf16)r0.x; h[1] = (__bf16)r0.y; h[2] = (__bf16)r0.z; h[3] = (__bf16)r0.w;
    h[4] = (__bf16)r1.x; h[5] = (__bf16)r1.y; h[6] = (__bf16)r1.z; h[7] = (__bf16)r1.w;
    *(bf16x8*)(R16 + (size_t)token * 512 + lane * 8) = h;
}

// ---------------------------------------------------------------------------
// Codebook prep (fused): c_sq[k] = ||cb[k]||^2 (fp32) and cb16 = bf16(cb)
// ---------------------------------------------------------------------------
__global__ __launch_bounds__(256)
void prep_cb(const float* __restrict__ CB, float* __restrict__ c_sq,
             __bf16* __restrict__ cb16)
{
    const int wave = threadIdx.x >> 6;
    const int lane = threadIdx.x & 63;
    const int row = blockIdx.x * 4 + wave;
    const float* p = CB + (size_t)row * DD + lane * 8;
    const float4 a = *(const float4*)p;
    const float4 b = *(const float4*)(p + 4);
    bf16x8 h;
    h[0] = (__bf16)a.x; h[1] = (__bf16)a.y; h[2] = (__bf16)a.z; h[3] = (__bf16)a.w;
    h[4] = (__bf16)b.x; h[5] = (__bf16)b.y; h[6] = (__bf16)b.z; h[7] = (__bf16)b.w;
    *(bf16x8*)(cb16 + (size_t)row * DD + lane * 8) = h;
    float s = a.x*a.x + a.y*a.y + a.z*a.z + a.w*a.w
            + b.x*b.x + b.y*b.y + b.z*b.z + b.w*b.w;
    #pragma unroll
    for (int m = 1; m < 64; m <<= 1) s += __shfl_xor(s, m, 64);
    if (lane == 0) c_sq[row] = s;
}

// ---------------------------------------------------------------------------
extern "C" void kernel_launch(void* const* d_in, const int* in_sizes, int n_in,
                              void* d_out, int out_size, void* d_ws, size_t ws_size,
                              hipStream_t stream)
{
    const float* x    = (const float*)d_in[0];
    const float* encw = (const float*)d_in[1];
    const float* encb = (const float*)d_in[2];
    const float* cb   = (const float*)d_in[3];
    const float* decw = (const float*)d_in[4];
    const float* decb = (const float*)d_in[5];
    float* out = (float*)d_out;

    // ws layout: z (32MB) | r (32MB) | cb16 (16MB) | r16 (16MB) | csq  (~96.1MB)
    float* z    = (float*)d_ws;                                  // TT*DD f32
    float* r    = z + (size_t)TT * DD;                           // TT*DD f32
    __bf16* cb16 = (__bf16*)(r + (size_t)TT * DD);               // KK*512 bf16
    __bf16* r16  = cb16 + (size_t)KK * DD;                       // TT*512 bf16
    float* csq  = (float*)(r16 + (size_t)TT * DD);               // KK f32
    // winners table lives in d_out (33.5 MB) — dead before decoder writes out
    uint32_t* winners = (uint32_t*)d_out;                        // TT*512 u32

    const dim3 blk(256);

    // encoder (MFMA hi/lo): z = x @ enc_w^T + enc_b ; r = z ; r16 = bf16(z)
    gemm_mfma<0><<<dim3(DD / 128, TT / 128), blk, 0, stream>>>(
        x, nullptr, encw, encb, z, r, r16);

    // codebook: exact squared norms + bf16 copy (fused, once per call)
    prep_cb<<<dim3(KK / 4), blk, 0, stream>>>(cb, csq, cb16);

    for (int s = 0; s < 2; ++s) {
        dist_approx<<<dim3(KK / 128, TT / 128), blk, 0, stream>>>(r16, cb16, csq, winners);
        select_rescore<<<dim3(TT / 4), blk, 0, stream>>>(winners, cb, csq, r, r16);
    }

    // decoder (MFMA hi/lo): out = (z - r) @ dec_w^T + dec_b
    gemm_mfma<1><<<dim3(DD / 128, TT / 128), blk, 0, stream>>>(
        z, r, decw, decb, out, nullptr, nullptr);
}